// Round 17
// baseline (147.378 us; speedup 1.0000x reference)
//
#include <hip/hip_runtime.h>
#include <hip/hip_bf16.h>
#include <cstdint>

#define NCAMS 6
#define NQ 2500
#define EMBED 256
#define HEADS 8
#define DHEAD 32
#define LTOT 19560
#define MVAL (NCAMS * LTOT) /* 117360 */
#define VP_GRID 612
#define VP_TILES 1834
#define SMP_GRID 625

typedef __attribute__((ext_vector_type(8))) short bf16x8;
typedef __attribute__((ext_vector_type(4))) float f32x4;

__device__ __forceinline__ unsigned short f2bf(float f) {
  unsigned u = __float_as_uint(f);
  return (unsigned short)((u + 0x7fffu + ((u >> 16) & 1u)) >> 16);
}
__device__ __forceinline__ unsigned short bfbits(float x) {
  __hip_bfloat16 h = __float2bfloat16(x);
  return __builtin_bit_cast(unsigned short, h);
}
__device__ __forceinline__ void gl16(const void* g, void* l) {
  __builtin_amdgcn_global_load_lds(
      (const __attribute__((address_space(1))) unsigned int*)g,
      (__attribute__((address_space(3))) unsigned int*)l, 16, 0, 0);
}

// ---------------------------------------------------------------------------
// Kernel P: weight transposes -> bf16 AND bev_mask -> valid.
// ---------------------------------------------------------------------------
__global__ __launch_bounds__(256) void k_prep(
    const float* __restrict__ Wv, const float* __restrict__ Woff,
    const float* __restrict__ Wattn, const float* __restrict__ Wout,
    const unsigned char* __restrict__ MSK,
    unsigned short* __restrict__ WT, unsigned short* __restrict__ WTq,
    unsigned short* __restrict__ WoutT,
    unsigned char* __restrict__ valid)
{
  const int b = blockIdx.x, t = threadIdx.x;
  if (b < 256) {
    WT[(size_t)b * 256 + t] = f2bf(Wv[(size_t)t * 256 + b]);
  } else if (b < 768) {
    int c = b - 256;
    WTq[(size_t)c * 256 + t] = f2bf(Woff[(size_t)t * 512 + c]);
  } else if (b < 1024) {
    int c = b - 768;
    WTq[(size_t)(512 + c) * 256 + t] = f2bf(Wattn[(size_t)t * 256 + c]);
  } else if (b < 1280) {
    int c = b - 1024;
    WoutT[(size_t)c * 256 + t] = f2bf(Wout[(size_t)t * 256 + c]);
  } else {
    __shared__ int s_u8;
    if (t == 0) s_u8 = 0;
    __syncthreads();
    if ((t & 3) && MSK[t]) atomicOr(&s_u8, 1);
    __syncthreads();
    const int isU8 = s_u8;
    const int i = (b - 1280) * 256 + t;
    if (i < NCAMS * NQ) {
      int any;
      if (isU8) {
        const unsigned char* p = MSK + (size_t)i * 4;
        any = p[0] | p[1] | p[2] | p[3];
      } else {
        const int* p = (const int*)MSK + (size_t)i * 4;
        any = p[0] | p[1] | p[2] | p[3];
      }
      valid[i] = any ? 1 : 0;
    }
  }
}

// ---------------------------------------------------------------------------
// Kernel A (v11): PERSISTENT grid (612 blocks, all co-resident at 3/CU;
// each does tiles b, b+612, b+1224 -> no scheduling tail). Body = r16 v9:
// fused convert+GEMM, global_load_lds w16, BM=64/BN=256/BK=64, 48KB LDS,
// 4-bit granule swizzle, swapped-operand MFMA, LDS-transpose epilogue.
// launch_bounds MUST stay (512,4) — r7 spill disaster at higher values.
// ---------------------------------------------------------------------------
__global__ __launch_bounds__(512, 4) void k_valproj(
    const float* __restrict__ A,            // (117360, 256) f32
    const unsigned short* __restrict__ WT,  // (256 cols, 256 k) bf16
    const float* __restrict__ bv,           // (256,)
    unsigned short* __restrict__ val)       // (117360, 256) bf16
{
  __shared__ unsigned int smemu[12288];                 // 48 KB
  float* Af = (float*)smemu;                            // [64][64] f32 (swizzled)
  unsigned short* Bs = (unsigned short*)(smemu + 4096); // [256][64] bf16 (swizzled)
  const int t = threadIdx.x;
  const int lane = t & 63;
  const int wid = t >> 6;
  const int wm = wid >> 2, wn = wid & 3;
  const int laneM = lane & 15, kGrp = lane >> 4;
  const int b3 = (laneM >> 3) & 1;

  // B staging sources (tile-invariant)
  const int sub = t >> 3;
  const int swz = (t & 7) ^ (sub & 7);
  const unsigned short* bS[4];
#pragma unroll
  for (int p = 0; p < 4; ++p)
    bS[p] = WT + (size_t)(p * 64 + sub) * 256 + swz * 8;

  // A-source row/granule decomposition (tile-invariant part)
  int aRow[2], aG4[2];
#pragma unroll
  for (int p = 0; p < 2; ++p) {
    int g16 = (wid * 2 + p) * 64 + lane;
    int row = g16 >> 4;
    int gl  = g16 & 15;
    aRow[p] = row;
    aG4[p]  = (gl ^ (((row & 7) << 1) | ((row >> 3) & 1))) * 4;
  }

  float4 bb4[4];
#pragma unroll
  for (int n = 0; n < 4; ++n)
    bb4[n] = *(const float4*)&bv[wn * 64 + n * 16 + kGrp * 4];

#pragma unroll 1
  for (int tile = blockIdx.x; tile < VP_TILES; tile += VP_GRID) {
    const int bm = tile * 64;
    if (tile != (int)blockIdx.x) __syncthreads();  // LDS reuse across tiles

    const float* aS[2];
#pragma unroll
    for (int p = 0; p < 2; ++p)
      aS[p] = A + (size_t)min(bm + aRow[p], MVAL - 1) * 256 + aG4[p];

    f32x4 acc[2][4];
#pragma unroll
    for (int m = 0; m < 2; ++m)
#pragma unroll
      for (int n = 0; n < 4; ++n) acc[m][n] = {0.f, 0.f, 0.f, 0.f};

#pragma unroll 1
    for (int kk = 0; kk < 4; ++kk) {
      if (kk) __syncthreads();
      const int koF = kk * 64;
#pragma unroll
      for (int p = 0; p < 2; ++p)
        gl16(aS[p] + koF, Af + (wid * 2 + p) * 256);
#pragma unroll
      for (int p = 0; p < 4; ++p)
        gl16(bS[p] + koF, Bs + p * 4096 + wid * 512);
      __syncthreads();

#pragma unroll
      for (int ks = 0; ks < 2; ++ks) {
        bf16x8 af[2], bfr[4];
#pragma unroll
        for (int m = 0; m < 2; ++m) {
          int row = wm * 32 + m * 16 + laneM;
          int u = (ks * 4 + kGrp) ^ (row & 7);
          const float* p8 = &Af[row * 64 + u * 8];
          float4 x = *(const float4*)(p8 + b3 * 4);
          float4 y = *(const float4*)(p8 + 4 - b3 * 4);
          union { bf16x8 v; unsigned short u16[8]; } c;
          c.u16[0] = bfbits(x.x); c.u16[1] = bfbits(x.y);
          c.u16[2] = bfbits(x.z); c.u16[3] = bfbits(x.w);
          c.u16[4] = bfbits(y.x); c.u16[5] = bfbits(y.y);
          c.u16[6] = bfbits(y.z); c.u16[7] = bfbits(y.w);
          af[m] = c.v;
        }
#pragma unroll
        for (int n = 0; n < 4; ++n) {
          int row = wn * 64 + n * 16 + laneM;
          bfr[n] = *(bf16x8*)&Bs[row * 64 + (((ks * 4 + kGrp) ^ (row & 7)) << 3)];
        }
#pragma unroll
        for (int m = 0; m < 2; ++m)
#pragma unroll
          for (int n = 0; n < 4; ++n)
            acc[m][n] = __builtin_amdgcn_mfma_f32_16x16x32_bf16(bfr[n], af[m], acc[m][n], 0, 0, 0);
      }
    }

    // epilogue: per-wave LDS transpose -> 128B contiguous stores
    __syncthreads();
    unsigned short* tlw = (unsigned short*)smemu + wid * (32 * 72);
#pragma unroll
    for (int m = 0; m < 2; ++m) {
#pragma unroll
      for (int n = 0; n < 4; ++n) {
        uint2 u;
        u.x = (unsigned)bfbits(acc[m][n][0] + bb4[n].x) |
              ((unsigned)bfbits(acc[m][n][1] + bb4[n].y) << 16);
        u.y = (unsigned)bfbits(acc[m][n][2] + bb4[n].z) |
              ((unsigned)bfbits(acc[m][n][3] + bb4[n].w) << 16);
        *(uint2*)&tlw[(m * 16 + laneM) * 72 + n * 16 + kGrp * 4] = u;
      }
    }
    __syncthreads();
#pragma unroll
    for (int i = 0; i < 4; ++i) {
      const int rowl = i * 8 + (lane >> 3);
      const int c8 = lane & 7;
      uint4 v = *(const uint4*)&tlw[rowl * 72 + c8 * 8];
      const int row = bm + wm * 32 + rowl;
      if (row < MVAL)
        *(uint4*)&val[(size_t)row * 256 + wn * 64 + c8 * 8] = v;
    }
  }
}

// ---------------------------------------------------------------------------
// Kernel Gq: OFFLOG gemm with fused f32->bf16 A conversion (A = query f32).
// ---------------------------------------------------------------------------
__global__ __launch_bounds__(256, 2) void k_gemm_qoff(
    const float* __restrict__ Aq,           // (2500, 256) f32
    const unsigned short* __restrict__ BT,  // (768, 256) bf16
    const float* __restrict__ ba, const float* __restrict__ bb, int bsplit,
    float* __restrict__ C, int M, int N)
{
  __shared__ unsigned short As[128 * 64];
  __shared__ unsigned short Bs[128 * 64];
  const int t = threadIdx.x;
  const int lane = t & 63;
  const int wid = t >> 6;
  const int wm = wid >> 1, wn = wid & 1;
  const int laneM = lane & 15, kGrp = lane >> 4;
  const int bm = blockIdx.x * 128;
  const int bn = blockIdx.y * 128;

  const int aC = t & 7, aR0 = t >> 3;

  float4 aRegs[2][4][2];
  uint4 bRegs[2][4];
  f32x4 acc[4][4];
#pragma unroll
  for (int m = 0; m < 4; ++m)
#pragma unroll
    for (int n = 0; n < 4; ++n) acc[m][n] = {0.f, 0.f, 0.f, 0.f};

#pragma unroll
  for (int p = 0; p < 4; ++p) {
    int arow = bm + aR0 + p * 32;
    if (arow < M) {
      const float* ap = &Aq[(size_t)arow * 256 + aC * 8];
      aRegs[0][p][0] = *(const float4*)ap;
      aRegs[0][p][1] = *(const float4*)(ap + 4);
    } else {
      aRegs[0][p][0] = aRegs[0][p][1] = make_float4(0.f, 0.f, 0.f, 0.f);
    }
    bRegs[0][p] = *(const uint4*)&BT[(size_t)(bn + aR0 + p * 32) * 256 + aC * 8];
  }

#pragma unroll
  for (int kk = 0; kk < 4; ++kk) {
    const int cur = kk & 1, nxt = cur ^ 1;
    if (kk) __syncthreads();
#pragma unroll
    for (int p = 0; p < 4; ++p) {
      int row = aR0 + p * 32;
      int elem = row * 64 + ((aC ^ (row & 7)) << 3);
      float4 x = aRegs[cur][p][0], y = aRegs[cur][p][1];
      uint4 u;
      u.x = (unsigned)f2bf(x.x) | ((unsigned)f2bf(x.y) << 16);
      u.y = (unsigned)f2bf(x.z) | ((unsigned)f2bf(x.w) << 16);
      u.z = (unsigned)f2bf(y.x) | ((unsigned)f2bf(y.y) << 16);
      u.w = (unsigned)f2bf(y.z) | ((unsigned)f2bf(y.w) << 16);
      *(uint4*)&As[elem] = u;
      *(uint4*)&Bs[elem] = bRegs[cur][p];
    }
    __syncthreads();
    if (kk < 3) {
      const int kn = (kk + 1) * 64;
#pragma unroll
      for (int p = 0; p < 4; ++p) {
        int arow = bm + aR0 + p * 32;
        if (arow < M) {
          const float* ap = &Aq[(size_t)arow * 256 + kn + aC * 8];
          aRegs[nxt][p][0] = *(const float4*)ap;
          aRegs[nxt][p][1] = *(const float4*)(ap + 4);
        } else {
          aRegs[nxt][p][0] = aRegs[nxt][p][1] = make_float4(0.f, 0.f, 0.f, 0.f);
        }
        bRegs[nxt][p] = *(const uint4*)&BT[(size_t)(bn + aR0 + p * 32) * 256 + kn + aC * 8];
      }
    }
#pragma unroll
    for (int ks = 0; ks < 2; ++ks) {
      bf16x8 af[4], bfr[4];
#pragma unroll
      for (int m = 0; m < 4; ++m) {
        int row = wm * 64 + m * 16 + laneM;
        af[m] = *(bf16x8*)&As[row * 64 + (((ks * 4 + kGrp) ^ (row & 7)) << 3)];
      }
#pragma unroll
      for (int n = 0; n < 4; ++n) {
        int row = wn * 64 + n * 16 + laneM;
        bfr[n] = *(bf16x8*)&Bs[row * 64 + (((ks * 4 + kGrp) ^ (row & 7)) << 3)];
      }
#pragma unroll
      for (int m = 0; m < 4; ++m)
#pragma unroll
        for (int n = 0; n < 4; ++n)
          acc[m][n] = __builtin_amdgcn_mfma_f32_16x16x32_bf16(af[m], bfr[n], acc[m][n], 0, 0, 0);
    }
  }

  float bvn[4];
#pragma unroll
  for (int n = 0; n < 4; ++n) {
    int col = bn + wn * 64 + n * 16 + laneM;
    bvn[n] = (col < bsplit) ? ba[col] : bb[col - bsplit];
  }
#pragma unroll
  for (int m = 0; m < 4; ++m) {
#pragma unroll
    for (int r = 0; r < 4; ++r) {
      int row = bm + wm * 64 + m * 16 + kGrp * 4 + r;
      if (row < M) {
#pragma unroll
        for (int n = 0; n < 4; ++n) {
          int col = bn + wn * 64 + n * 16 + laneM;
          C[(size_t)row * N + col] = acc[m][n][r] + bvn[n];
        }
      }
    }
  }
}

// ---------------------------------------------------------------------------
// Kernel G: generic small-M bf16 GEMM (outproj, with residual).
// ---------------------------------------------------------------------------
__global__ __launch_bounds__(256, 2) void k_gemm_small(
    const unsigned short* __restrict__ A,
    const unsigned short* __restrict__ BT,
    const float* __restrict__ ba, const float* __restrict__ bb, int bsplit,
    const float* __restrict__ resid,
    float* __restrict__ C, int M, int N, int withResid)
{
  __shared__ unsigned short As[128 * 64];
  __shared__ unsigned short Bs[128 * 64];
  const int t = threadIdx.x;
  const int lane = t & 63;
  const int wid = t >> 6;
  const int wm = wid >> 1, wn = wid & 1;
  const int laneM = lane & 15, kGrp = lane >> 4;
  const int bm = blockIdx.x * 128;
  const int bn = blockIdx.y * 128;

  const int aC = t & 7, aR0 = t >> 3;

  uint4 aRegs[2][4];
  uint4 bRegs[2][4];
  f32x4 acc[4][4];
#pragma unroll
  for (int m = 0; m < 4; ++m)
#pragma unroll
    for (int n = 0; n < 4; ++n) acc[m][n] = {0.f, 0.f, 0.f, 0.f};

#pragma unroll
  for (int p = 0; p < 4; ++p) {
    int arow = bm + aR0 + p * 32;
    aRegs[0][p] = (arow < M) ? *(const uint4*)&A[(size_t)arow * 256 + aC * 8]
                             : make_uint4(0u, 0u, 0u, 0u);
    bRegs[0][p] = *(const uint4*)&BT[(size_t)(bn + aR0 + p * 32) * 256 + aC * 8];
  }

#pragma unroll
  for (int kk = 0; kk < 4; ++kk) {
    const int cur = kk & 1, nxt = cur ^ 1;
    if (kk) __syncthreads();
#pragma unroll
    for (int p = 0; p < 4; ++p) {
      int row = aR0 + p * 32;
      int elem = row * 64 + ((aC ^ (row & 7)) << 3);
      *(uint4*)&As[elem] = aRegs[cur][p];
      *(uint4*)&Bs[elem] = bRegs[cur][p];
    }
    __syncthreads();
    if (kk < 3) {
      const int kn = (kk + 1) * 64;
#pragma unroll
      for (int p = 0; p < 4; ++p) {
        int arow = bm + aR0 + p * 32;
        aRegs[nxt][p] = (arow < M)
            ? *(const uint4*)&A[(size_t)arow * 256 + kn + aC * 8]
            : make_uint4(0u, 0u, 0u, 0u);
        bRegs[nxt][p] = *(const uint4*)&BT[(size_t)(bn + aR0 + p * 32) * 256 + kn + aC * 8];
      }
    }
#pragma unroll
    for (int ks = 0; ks < 2; ++ks) {
      bf16x8 af[4], bfr[4];
#pragma unroll
      for (int m = 0; m < 4; ++m) {
        int row = wm * 64 + m * 16 + laneM;
        af[m] = *(bf16x8*)&As[row * 64 + (((ks * 4 + kGrp) ^ (row & 7)) << 3)];
      }
#pragma unroll
      for (int n = 0; n < 4; ++n) {
        int row = wn * 64 + n * 16 + laneM;
        bfr[n] = *(bf16x8*)&Bs[row * 64 + (((ks * 4 + kGrp) ^ (row & 7)) << 3)];
      }
#pragma unroll
      for (int m = 0; m < 4; ++m)
#pragma unroll
        for (int n = 0; n < 4; ++n)
          acc[m][n] = __builtin_amdgcn_mfma_f32_16x16x32_bf16(af[m], bfr[n], acc[m][n], 0, 0, 0);
    }
  }

  float bvn[4];
#pragma unroll
  for (int n = 0; n < 4; ++n) {
    int col = bn + wn * 64 + n * 16 + laneM;
    bvn[n] = (col < bsplit) ? ba[col] : bb[col - bsplit];
  }
#pragma unroll
  for (int m = 0; m < 4; ++m) {
#pragma unroll
    for (int r = 0; r < 4; ++r) {
      int row = bm + wm * 64 + m * 16 + kGrp * 4 + r;
      if (row < M) {
#pragma unroll
        for (int n = 0; n < 4; ++n) {
          int col = bn + wn * 64 + n * 16 + laneM;
          float v = acc[m][n][r] + bvn[n];
          if (withResid) v += resid[(size_t)row * 256 + col];
          C[(size_t)row * N + col] = v;
        }
      }
    }
  }
}

// ---------------------------------------------------------------------------
// Kernel C (v4): PERSISTENT two-phase sampling (625 blocks x 4 queries,
// all co-resident at 3/CU -> no scheduling tail). Body = r16 v3.
// ---------------------------------------------------------------------------
__global__ __launch_bounds__(256) void k_sample(
    const unsigned short* __restrict__ val,   // (117360, 256) bf16
    const float* __restrict__ OFFLOG,         // (2500, 768)
    const float* __restrict__ REF,            // (6,1,2500,4,2)
    const unsigned char* __restrict__ valid,  // (6,2500)
    unsigned short* __restrict__ slots)       // (2500,256) bf16
{
  __shared__ int2  s_pack[4][NCAMS][256];
  __shared__ float s_off[512];
  __shared__ float s_ref[48];
  __shared__ int   s_valid[6];

  const int t = threadIdx.x;

#pragma unroll 1
  for (int qi = 0; qi < 4; ++qi) {
    const int q = (int)blockIdx.x + qi * SMP_GRID;
    if (qi) __syncthreads();  // protect LDS reuse across iterations

    s_off[t]       = OFFLOG[(size_t)q * 768 + t];
    s_off[t + 256] = OFFLOG[(size_t)q * 768 + 256 + t];
    if (t < 48) s_ref[t] = REF[(size_t)(t >> 3) * (NQ * 8) + (size_t)q * 8 + (t & 7)];
    if (t < 6) s_valid[t] = valid[(size_t)t * NQ + q];

    float logit = OFFLOG[(size_t)q * 768 + 512 + t];
    float m = logit;
#pragma unroll
    for (int o = 16; o > 0; o >>= 1) m = fmaxf(m, __shfl_xor(m, o, 32));
    float e = __expf(logit - m);
    float s = e;
#pragma unroll
    for (int o = 16; o > 0; o >>= 1) s += __shfl_xor(s, o, 32);
    const float a = e / s;
    __syncthreads();

    // ---- phase 1: per-tuple corner addresses & weights ----
    {
      const int h1 = t >> 5, lp = t & 31, lvl = lp >> 3, p = lp & 7, z = p & 3;
      const int WW = 160 >> lvl;
      const int HH = (lvl < 3) ? (92 >> lvl) : 12;
      const int S  = (lvl == 0) ? 0 : (lvl == 1) ? 14720 : (lvl == 2) ? 18400 : 19320;
      const float Wf = (float)WW, Hf = (float)HH;
      const float ox = s_off[h1 * 64 + lp * 2];
      const float oy = s_off[h1 * 64 + lp * 2 + 1];
#pragma unroll 1
      for (int cam = 0; cam < NCAMS; ++cam) {
        if (!s_valid[cam]) continue;
        float rx = s_ref[cam * 8 + z * 2];
        float ry = s_ref[cam * 8 + z * 2 + 1];
        float x = rx * Wf + ox - 0.5f;
        float y = ry * Hf + oy - 0.5f;
        float x0f = floorf(x), y0f = floorf(y);
        float fx = x - x0f, fy = y - y0f;
        int x0 = (int)x0f, y0 = (int)y0f;
        int base = cam * LTOT + S;
#pragma unroll
        for (int dy = 0; dy < 2; ++dy) {
          int yi = y0 + dy;
          float wy = dy ? fy : 1.f - fy;
          int yc = min(max(yi, 0), HH - 1);
          bool vy = (yi >= 0) && (yi < HH);
#pragma unroll
          for (int dx = 0; dx < 2; ++dx) {
            int xi = x0 + dx;
            float wx = dx ? fx : 1.f - fx;
            int xc = min(max(xi, 0), WW - 1);
            bool vv = vy && (xi >= 0) && (xi < WW);
            float wgt = vv ? wx * wy * a : 0.f;
            int addr = (base + yc * WW + xc) * 512;
            s_pack[dy * 2 + dx][cam][t] = make_int2(addr, __float_as_int(wgt));
          }
        }
      }
    }
    __syncthreads();

    // ---- phase 2: uint4 gathers (8 d's per lane) ----
    const int h = t >> 5, pp = (t >> 2) & 7, l4 = t & 3;
    const unsigned dconst = (unsigned)(h * 64 + l4 * 16);
    const char* vb = (const char*)val;
    int nvalid = s_valid[0] + s_valid[1] + s_valid[2] + s_valid[3] + s_valid[4] + s_valid[5];
    float inv = 1.f / fmaxf((float)nvalid, 1.f);

    float a0 = 0.f, a1 = 0.f, a2 = 0.f, a3 = 0.f;
    float a4 = 0.f, a5 = 0.f, a6 = 0.f, a7 = 0.f;
#pragma unroll 1
    for (int cam = 0; cam < NCAMS; ++cam) {
      if (!s_valid[cam]) continue;
#pragma unroll
      for (int it = 0; it < 4; ++it) {
        const int idx = h * 32 + it * 8 + pp;
        int2 pk0 = s_pack[0][cam][idx];
        int2 pk1 = s_pack[1][cam][idx];
        int2 pk2 = s_pack[2][cam][idx];
        int2 pk3 = s_pack[3][cam][idx];
        uint4 v0 = *(const uint4*)(vb + (size_t)((unsigned)pk0.x + dconst));
        uint4 v1 = *(const uint4*)(vb + (size_t)((unsigned)pk1.x + dconst));
        uint4 v2 = *(const uint4*)(vb + (size_t)((unsigned)pk2.x + dconst));
        uint4 v3 = *(const uint4*)(vb + (size_t)((unsigned)pk3.x + dconst));
        float w0 = __int_as_float(pk0.y), w1 = __int_as_float(pk1.y);
        float w2 = __int_as_float(pk2.y), w3 = __int_as_float(pk3.y);
        a0 += w0 * __uint_as_float(v0.x << 16);
        a1 += w0 * __uint_as_float(v0.x & 0xffff0000u);
        a2 += w0 * __uint_as_float(v0.y << 16);
        a3 += w0 * __uint_as_float(v0.y & 0xffff0000u);
        a4 += w0 * __uint_as_float(v0.z << 16);
        a5 += w0 * __uint_as_float(v0.z & 0xffff0000u);
        a6 += w0 * __uint_as_float(v0.w << 16);
        a7 += w0 * __uint_as_float(v0.w & 0xffff0000u);
        a0 += w1 * __uint_as_float(v1.x << 16);
        a1 += w1 * __uint_as_float(v1.x & 0xffff0000u);
        a2 += w1 * __uint_as_float(v1.y << 16);
        a3 += w1 * __uint_as_float(v1.y & 0xffff0000u);
        a4 += w1 * __uint_as_float(v1.z << 16);
        a5 += w1 * __uint_as_float(v1.z & 0xffff0000u);
        a6 += w1 * __uint_as_float(v1.w << 16);
        a7 += w1 * __uint_as_float(v1.w & 0xffff0000u);
        a0 += w2 * __uint_as_float(v2.x << 16);
        a1 += w2 * __uint_as_float(v2.x & 0xffff0000u);
        a2 += w2 * __uint_as_float(v2.y << 16);
        a3 += w2 * __uint_as_float(v2.y & 0xffff0000u);
        a4 += w2 * __uint_as_float(v2.z << 16);
        a5 += w2 * __uint_as_float(v2.z & 0xffff0000u);
        a6 += w2 * __uint_as_float(v2.w << 16);
        a7 += w2 * __uint_as_float(v2.w & 0xffff0000u);
        a0 += w3 * __uint_as_float(v3.x << 16);
        a1 += w3 * __uint_as_float(v3.x & 0xffff0000u);
        a2 += w3 * __uint_as_float(v3.y << 16);
        a3 += w3 * __uint_as_float(v3.y & 0xffff0000u);
        a4 += w3 * __uint_as_float(v3.z << 16);
        a5 += w3 * __uint_as_float(v3.z & 0xffff0000u);
        a6 += w3 * __uint_as_float(v3.w << 16);
        a7 += w3 * __uint_as_float(v3.w & 0xffff0000u);
      }
    }

#pragma unroll
    for (int o = 4; o <= 16; o <<= 1) {
      a0 += __shfl_xor(a0, o); a1 += __shfl_xor(a1, o);
      a2 += __shfl_xor(a2, o); a3 += __shfl_xor(a3, o);
      a4 += __shfl_xor(a4, o); a5 += __shfl_xor(a5, o);
      a6 += __shfl_xor(a6, o); a7 += __shfl_xor(a7, o);
    }
    if (pp == 0) {
      uint4 r;
      r.x = (unsigned)f2bf(a0 * inv) | ((unsigned)f2bf(a1 * inv) << 16);
      r.y = (unsigned)f2bf(a2 * inv) | ((unsigned)f2bf(a3 * inv) << 16);
      r.z = (unsigned)f2bf(a4 * inv) | ((unsigned)f2bf(a5 * inv) << 16);
      r.w = (unsigned)f2bf(a6 * inv) | ((unsigned)f2bf(a7 * inv) << 16);
      *(uint4*)&slots[(size_t)q * 256 + h * 32 + l4 * 8] = r;
    }
  }
}

// ---------------------------------------------------------------------------
extern "C" void kernel_launch(void* const* d_in, const int* in_sizes, int n_in,
                              void* d_out, int out_size, void* d_ws, size_t ws_size,
                              hipStream_t stream) {
  const float* query     = (const float*)d_in[0];
  const float* key_feats = (const float*)d_in[1];
  const float* ref       = (const float*)d_in[2];
  const unsigned char* mask = (const unsigned char*)d_in[3];
  // d_in[4] = spatial_shapes (compile-time constants)
  const float* Wv    = (const float*)d_in[5];
  const float* bv    = (const float*)d_in[6];
  const float* Woff  = (const float*)d_in[7];
  const float* boff  = (const float*)d_in[8];
  const float* Wattn = (const float*)d_in[9];
  const float* battn = (const float*)d_in[10];
  const float* Wout  = (const float*)d_in[11];
  const float* bout  = (const float*)d_in[12];
  float* out = (float*)d_out;

  char* ws = (char*)d_ws;
  size_t off = 0;
  unsigned short* val   = (unsigned short*)(ws + off); off += (size_t)MVAL * 256 * 2;
  unsigned short* WT    = (unsigned short*)(ws + off); off += 256 * 256 * 2;
  unsigned short* WTq   = (unsigned short*)(ws + off); off += 768 * 256 * 2;
  unsigned short* WoutT = (unsigned short*)(ws + off); off += 256 * 256 * 2;
  float* OFFLOG = (float*)(ws + off); off += (size_t)NQ * 768 * 4;
  unsigned short* slots = (unsigned short*)(ws + off); off += (size_t)NQ * 256 * 2;
  unsigned char* valid  = (unsigned char*)(ws + off); off += NCAMS * NQ;

  const int MASKBLKS = (NCAMS * NQ + 255) / 256;  // 59
  hipLaunchKernelGGL(k_prep, dim3(1280 + MASKBLKS), dim3(256), 0, stream,
                     Wv, Woff, Wattn, Wout, mask, WT, WTq, WoutT, valid);
  hipLaunchKernelGGL(k_valproj, dim3(VP_GRID), dim3(512), 0, stream,
                     key_feats, WT, bv, val);
  hipLaunchKernelGGL(k_gemm_qoff, dim3((NQ + 127) / 128, 6), dim3(256), 0, stream,
                     query, WTq, boff, battn, 512, OFFLOG, NQ, 768);
  hipLaunchKernelGGL(k_sample, dim3(SMP_GRID), dim3(256), 0, stream,
                     val, OFFLOG, ref, valid, slots);
  hipLaunchKernelGGL(k_gemm_small, dim3((NQ + 127) / 128, 2), dim3(256), 0, stream,
                     slots, WoutT, bout, bout, 1 << 30, query, out, NQ, 256, 1);
}

// Round 18
// 136.949 us; speedup vs baseline: 1.0762x; 1.0762x over previous
//
#include <hip/hip_runtime.h>
#include <hip/hip_bf16.h>
#include <cstdint>

#define NCAMS 6
#define NQ 2500
#define EMBED 256
#define HEADS 8
#define DHEAD 32
#define LTOT 19560
#define MVAL (NCAMS * LTOT) /* 117360 */

typedef __attribute__((ext_vector_type(8))) short bf16x8;
typedef __attribute__((ext_vector_type(4))) float f32x4;

__device__ __forceinline__ unsigned short f2bf(float f) {
  unsigned u = __float_as_uint(f);
  return (unsigned short)((u + 0x7fffu + ((u >> 16) & 1u)) >> 16);
}
__device__ __forceinline__ unsigned short bfbits(float x) {
  __hip_bfloat16 h = __float2bfloat16(x);
  return __builtin_bit_cast(unsigned short, h);
}
__device__ __forceinline__ void gl16(const void* g, void* l) {
  __builtin_amdgcn_global_load_lds(
      (const __attribute__((address_space(1))) unsigned int*)g,
      (__attribute__((address_space(3))) unsigned int*)l, 16, 0, 0);
}

// ---------------------------------------------------------------------------
// Kernel P: weight transposes -> bf16 AND bev_mask -> valid.
// ---------------------------------------------------------------------------
__global__ __launch_bounds__(256) void k_prep(
    const float* __restrict__ Wv, const float* __restrict__ Woff,
    const float* __restrict__ Wattn, const float* __restrict__ Wout,
    const unsigned char* __restrict__ MSK,
    unsigned short* __restrict__ WT, unsigned short* __restrict__ WTq,
    unsigned short* __restrict__ WoutT,
    unsigned char* __restrict__ valid)
{
  const int b = blockIdx.x, t = threadIdx.x;
  if (b < 256) {
    WT[(size_t)b * 256 + t] = f2bf(Wv[(size_t)t * 256 + b]);
  } else if (b < 768) {
    int c = b - 256;
    WTq[(size_t)c * 256 + t] = f2bf(Woff[(size_t)t * 512 + c]);
  } else if (b < 1024) {
    int c = b - 768;
    WTq[(size_t)(512 + c) * 256 + t] = f2bf(Wattn[(size_t)t * 256 + c]);
  } else if (b < 1280) {
    int c = b - 1024;
    WoutT[(size_t)c * 256 + t] = f2bf(Wout[(size_t)t * 256 + c]);
  } else {
    __shared__ int s_u8;
    if (t == 0) s_u8 = 0;
    __syncthreads();
    if ((t & 3) && MSK[t]) atomicOr(&s_u8, 1);
    __syncthreads();
    const int isU8 = s_u8;
    const int i = (b - 1280) * 256 + t;
    if (i < NCAMS * NQ) {
      int any;
      if (isU8) {
        const unsigned char* p = MSK + (size_t)i * 4;
        any = p[0] | p[1] | p[2] | p[3];
      } else {
        const int* p = (const int*)MSK + (size_t)i * 4;
        any = p[0] | p[1] | p[2] | p[3];
      }
      valid[i] = any ? 1 : 0;
    }
  }
}

// ---------------------------------------------------------------------------
// Kernel A (v9, the measured-best structure from r14/r16):
// val = bf16( A_f32 @ W_value + b_value ). Fused convert+GEMM,
// global_load_lds w16, BM=64/BN=256/BK=64, 48KB LDS -> 3 blocks/CU,
// 4-bit granule swizzle (conflict-free), swapped-operand MFMA, per-wave
// LDS-transpose epilogue (ideal WRITE_SIZE).
// Rejected by measurement: BK=32 counted-vmcnt dbuf (r15, +5us),
// persistent 612-block grid (r17, +4us), launch_bounds>4 (r7, spill).
// ---------------------------------------------------------------------------
__global__ __launch_bounds__(512, 4) void k_valproj(
    const float* __restrict__ A,            // (117360, 256) f32
    const unsigned short* __restrict__ WT,  // (256 cols, 256 k) bf16
    const float* __restrict__ bv,           // (256,)
    unsigned short* __restrict__ val)       // (117360, 256) bf16
{
  __shared__ unsigned int smemu[12288];                 // 48 KB
  float* Af = (float*)smemu;                            // [64][64] f32 (swizzled)
  unsigned short* Bs = (unsigned short*)(smemu + 4096); // [256][64] bf16 (swizzled)
  const int t = threadIdx.x;
  const int lane = t & 63;
  const int wid = t >> 6;
  const int wm = wid >> 2, wn = wid & 3;
  const int laneM = lane & 15, kGrp = lane >> 4;
  const int b3 = (laneM >> 3) & 1;
  const int bm = blockIdx.x * 64;

  const float* aS[2];
#pragma unroll
  for (int p = 0; p < 2; ++p) {
    int g16 = (wid * 2 + p) * 64 + lane;
    int row = g16 >> 4;
    int gl  = g16 & 15;
    int g   = gl ^ (((row & 7) << 1) | ((row >> 3) & 1));
    aS[p] = A + (size_t)min(bm + row, MVAL - 1) * 256 + g * 4;
  }
  const int sub = t >> 3;
  const int swz = (t & 7) ^ (sub & 7);
  const unsigned short* bS[4];
#pragma unroll
  for (int p = 0; p < 4; ++p)
    bS[p] = WT + (size_t)(p * 64 + sub) * 256 + swz * 8;

  f32x4 acc[2][4];
#pragma unroll
  for (int m = 0; m < 2; ++m)
#pragma unroll
    for (int n = 0; n < 4; ++n) acc[m][n] = {0.f, 0.f, 0.f, 0.f};

#pragma unroll 1
  for (int kk = 0; kk < 4; ++kk) {
    if (kk) __syncthreads();
    const int koF = kk * 64;
#pragma unroll
    for (int p = 0; p < 2; ++p)
      gl16(aS[p] + koF, Af + (wid * 2 + p) * 256);
#pragma unroll
    for (int p = 0; p < 4; ++p)
      gl16(bS[p] + koF, Bs + p * 4096 + wid * 512);
    __syncthreads();

#pragma unroll
    for (int ks = 0; ks < 2; ++ks) {
      bf16x8 af[2], bfr[4];
#pragma unroll
      for (int m = 0; m < 2; ++m) {
        int row = wm * 32 + m * 16 + laneM;
        int u = (ks * 4 + kGrp) ^ (row & 7);
        const float* p8 = &Af[row * 64 + u * 8];
        float4 x = *(const float4*)(p8 + b3 * 4);
        float4 y = *(const float4*)(p8 + 4 - b3 * 4);
        union { bf16x8 v; unsigned short u16[8]; } c;
        c.u16[0] = bfbits(x.x); c.u16[1] = bfbits(x.y);
        c.u16[2] = bfbits(x.z); c.u16[3] = bfbits(x.w);
        c.u16[4] = bfbits(y.x); c.u16[5] = bfbits(y.y);
        c.u16[6] = bfbits(y.z); c.u16[7] = bfbits(y.w);
        af[m] = c.v;
      }
#pragma unroll
      for (int n = 0; n < 4; ++n) {
        int row = wn * 64 + n * 16 + laneM;
        bfr[n] = *(bf16x8*)&Bs[row * 64 + (((ks * 4 + kGrp) ^ (row & 7)) << 3)];
      }
#pragma unroll
      for (int m = 0; m < 2; ++m)
#pragma unroll
        for (int n = 0; n < 4; ++n)
          acc[m][n] = __builtin_amdgcn_mfma_f32_16x16x32_bf16(bfr[n], af[m], acc[m][n], 0, 0, 0);
    }
  }

  float4 bb4[4];
#pragma unroll
  for (int n = 0; n < 4; ++n)
    bb4[n] = *(const float4*)&bv[wn * 64 + n * 16 + kGrp * 4];

  __syncthreads();
  unsigned short* tlw = (unsigned short*)smemu + wid * (32 * 72);

#pragma unroll
  for (int m = 0; m < 2; ++m) {
#pragma unroll
    for (int n = 0; n < 4; ++n) {
      uint2 u;
      u.x = (unsigned)bfbits(acc[m][n][0] + bb4[n].x) |
            ((unsigned)bfbits(acc[m][n][1] + bb4[n].y) << 16);
      u.y = (unsigned)bfbits(acc[m][n][2] + bb4[n].z) |
            ((unsigned)bfbits(acc[m][n][3] + bb4[n].w) << 16);
      *(uint2*)&tlw[(m * 16 + laneM) * 72 + n * 16 + kGrp * 4] = u;
    }
  }
  __syncthreads();
#pragma unroll
  for (int i = 0; i < 4; ++i) {
    const int rowl = i * 8 + (lane >> 3);
    const int c8 = lane & 7;
    uint4 v = *(const uint4*)&tlw[rowl * 72 + c8 * 8];
    const int row = bm + wm * 32 + rowl;
    if (row < MVAL)
      *(uint4*)&val[(size_t)row * 256 + wn * 64 + c8 * 8] = v;
  }
}

// ---------------------------------------------------------------------------
// Kernel Gq: OFFLOG gemm with fused f32->bf16 A conversion (A = query f32).
// ---------------------------------------------------------------------------
__global__ __launch_bounds__(256, 2) void k_gemm_qoff(
    const float* __restrict__ Aq,           // (2500, 256) f32
    const unsigned short* __restrict__ BT,  // (768, 256) bf16
    const float* __restrict__ ba, const float* __restrict__ bb, int bsplit,
    float* __restrict__ C, int M, int N)
{
  __shared__ unsigned short As[128 * 64];
  __shared__ unsigned short Bs[128 * 64];
  const int t = threadIdx.x;
  const int lane = t & 63;
  const int wid = t >> 6;
  const int wm = wid >> 1, wn = wid & 1;
  const int laneM = lane & 15, kGrp = lane >> 4;
  const int bm = blockIdx.x * 128;
  const int bn = blockIdx.y * 128;

  const int aC = t & 7, aR0 = t >> 3;

  float4 aRegs[2][4][2];
  uint4 bRegs[2][4];
  f32x4 acc[4][4];
#pragma unroll
  for (int m = 0; m < 4; ++m)
#pragma unroll
    for (int n = 0; n < 4; ++n) acc[m][n] = {0.f, 0.f, 0.f, 0.f};

#pragma unroll
  for (int p = 0; p < 4; ++p) {
    int arow = bm + aR0 + p * 32;
    if (arow < M) {
      const float* ap = &Aq[(size_t)arow * 256 + aC * 8];
      aRegs[0][p][0] = *(const float4*)ap;
      aRegs[0][p][1] = *(const float4*)(ap + 4);
    } else {
      aRegs[0][p][0] = aRegs[0][p][1] = make_float4(0.f, 0.f, 0.f, 0.f);
    }
    bRegs[0][p] = *(const uint4*)&BT[(size_t)(bn + aR0 + p * 32) * 256 + aC * 8];
  }

#pragma unroll
  for (int kk = 0; kk < 4; ++kk) {
    const int cur = kk & 1, nxt = cur ^ 1;
    if (kk) __syncthreads();
#pragma unroll
    for (int p = 0; p < 4; ++p) {
      int row = aR0 + p * 32;
      int elem = row * 64 + ((aC ^ (row & 7)) << 3);
      float4 x = aRegs[cur][p][0], y = aRegs[cur][p][1];
      uint4 u;
      u.x = (unsigned)f2bf(x.x) | ((unsigned)f2bf(x.y) << 16);
      u.y = (unsigned)f2bf(x.z) | ((unsigned)f2bf(x.w) << 16);
      u.z = (unsigned)f2bf(y.x) | ((unsigned)f2bf(y.y) << 16);
      u.w = (unsigned)f2bf(y.z) | ((unsigned)f2bf(y.w) << 16);
      *(uint4*)&As[elem] = u;
      *(uint4*)&Bs[elem] = bRegs[cur][p];
    }
    __syncthreads();
    if (kk < 3) {
      const int kn = (kk + 1) * 64;
#pragma unroll
      for (int p = 0; p < 4; ++p) {
        int arow = bm + aR0 + p * 32;
        if (arow < M) {
          const float* ap = &Aq[(size_t)arow * 256 + kn + aC * 8];
          aRegs[nxt][p][0] = *(const float4*)ap;
          aRegs[nxt][p][1] = *(const float4*)(ap + 4);
        } else {
          aRegs[nxt][p][0] = aRegs[nxt][p][1] = make_float4(0.f, 0.f, 0.f, 0.f);
        }
        bRegs[nxt][p] = *(const uint4*)&BT[(size_t)(bn + aR0 + p * 32) * 256 + kn + aC * 8];
      }
    }
#pragma unroll
    for (int ks = 0; ks < 2; ++ks) {
      bf16x8 af[4], bfr[4];
#pragma unroll
      for (int m = 0; m < 4; ++m) {
        int row = wm * 64 + m * 16 + laneM;
        af[m] = *(bf16x8*)&As[row * 64 + (((ks * 4 + kGrp) ^ (row & 7)) << 3)];
      }
#pragma unroll
      for (int n = 0; n < 4; ++n) {
        int row = wn * 64 + n * 16 + laneM;
        bfr[n] = *(bf16x8*)&Bs[row * 64 + (((ks * 4 + kGrp) ^ (row & 7)) << 3)];
      }
#pragma unroll
      for (int m = 0; m < 4; ++m)
#pragma unroll
        for (int n = 0; n < 4; ++n)
          acc[m][n] = __builtin_amdgcn_mfma_f32_16x16x32_bf16(af[m], bfr[n], acc[m][n], 0, 0, 0);
    }
  }

  float bvn[4];
#pragma unroll
  for (int n = 0; n < 4; ++n) {
    int col = bn + wn * 64 + n * 16 + laneM;
    bvn[n] = (col < bsplit) ? ba[col] : bb[col - bsplit];
  }
#pragma unroll
  for (int m = 0; m < 4; ++m) {
#pragma unroll
    for (int r = 0; r < 4; ++r) {
      int row = bm + wm * 64 + m * 16 + kGrp * 4 + r;
      if (row < M) {
#pragma unroll
        for (int n = 0; n < 4; ++n) {
          int col = bn + wn * 64 + n * 16 + laneM;
          C[(size_t)row * N + col] = acc[m][n][r] + bvn[n];
        }
      }
    }
  }
}

// ---------------------------------------------------------------------------
// Kernel G: generic small-M bf16 GEMM (outproj, with residual).
// ---------------------------------------------------------------------------
__global__ __launch_bounds__(256, 2) void k_gemm_small(
    const unsigned short* __restrict__ A,
    const unsigned short* __restrict__ BT,
    const float* __restrict__ ba, const float* __restrict__ bb, int bsplit,
    const float* __restrict__ resid,
    float* __restrict__ C, int M, int N, int withResid)
{
  __shared__ unsigned short As[128 * 64];
  __shared__ unsigned short Bs[128 * 64];
  const int t = threadIdx.x;
  const int lane = t & 63;
  const int wid = t >> 6;
  const int wm = wid >> 1, wn = wid & 1;
  const int laneM = lane & 15, kGrp = lane >> 4;
  const int bm = blockIdx.x * 128;
  const int bn = blockIdx.y * 128;

  const int aC = t & 7, aR0 = t >> 3;

  uint4 aRegs[2][4];
  uint4 bRegs[2][4];
  f32x4 acc[4][4];
#pragma unroll
  for (int m = 0; m < 4; ++m)
#pragma unroll
    for (int n = 0; n < 4; ++n) acc[m][n] = {0.f, 0.f, 0.f, 0.f};

#pragma unroll
  for (int p = 0; p < 4; ++p) {
    int arow = bm + aR0 + p * 32;
    aRegs[0][p] = (arow < M) ? *(const uint4*)&A[(size_t)arow * 256 + aC * 8]
                             : make_uint4(0u, 0u, 0u, 0u);
    bRegs[0][p] = *(const uint4*)&BT[(size_t)(bn + aR0 + p * 32) * 256 + aC * 8];
  }

#pragma unroll
  for (int kk = 0; kk < 4; ++kk) {
    const int cur = kk & 1, nxt = cur ^ 1;
    if (kk) __syncthreads();
#pragma unroll
    for (int p = 0; p < 4; ++p) {
      int row = aR0 + p * 32;
      int elem = row * 64 + ((aC ^ (row & 7)) << 3);
      *(uint4*)&As[elem] = aRegs[cur][p];
      *(uint4*)&Bs[elem] = bRegs[cur][p];
    }
    __syncthreads();
    if (kk < 3) {
      const int kn = (kk + 1) * 64;
#pragma unroll
      for (int p = 0; p < 4; ++p) {
        int arow = bm + aR0 + p * 32;
        aRegs[nxt][p] = (arow < M)
            ? *(const uint4*)&A[(size_t)arow * 256 + kn + aC * 8]
            : make_uint4(0u, 0u, 0u, 0u);
        bRegs[nxt][p] = *(const uint4*)&BT[(size_t)(bn + aR0 + p * 32) * 256 + kn + aC * 8];
      }
    }
#pragma unroll
    for (int ks = 0; ks < 2; ++ks) {
      bf16x8 af[4], bfr[4];
#pragma unroll
      for (int m = 0; m < 4; ++m) {
        int row = wm * 64 + m * 16 + laneM;
        af[m] = *(bf16x8*)&As[row * 64 + (((ks * 4 + kGrp) ^ (row & 7)) << 3)];
      }
#pragma unroll
      for (int n = 0; n < 4; ++n) {
        int row = wn * 64 + n * 16 + laneM;
        bfr[n] = *(bf16x8*)&Bs[row * 64 + (((ks * 4 + kGrp) ^ (row & 7)) << 3)];
      }
#pragma unroll
      for (int m = 0; m < 4; ++m)
#pragma unroll
        for (int n = 0; n < 4; ++n)
          acc[m][n] = __builtin_amdgcn_mfma_f32_16x16x32_bf16(af[m], bfr[n], acc[m][n], 0, 0, 0);
    }
  }

  float bvn[4];
#pragma unroll
  for (int n = 0; n < 4; ++n) {
    int col = bn + wn * 64 + n * 16 + laneM;
    bvn[n] = (col < bsplit) ? ba[col] : bb[col - bsplit];
  }
#pragma unroll
  for (int m = 0; m < 4; ++m) {
#pragma unroll
    for (int r = 0; r < 4; ++r) {
      int row = bm + wm * 64 + m * 16 + kGrp * 4 + r;
      if (row < M) {
#pragma unroll
        for (int n = 0; n < 4; ++n) {
          int col = bn + wn * 64 + n * 16 + laneM;
          float v = acc[m][n][r] + bvn[n];
          if (withResid) v += resid[(size_t)row * 256 + col];
          C[(size_t)row * N + col] = v;
        }
      }
    }
  }
}

// ---------------------------------------------------------------------------
// Kernel C (v3): two-phase sampling with uint4 gathers (r14/r16 best).
// ---------------------------------------------------------------------------
__global__ __launch_bounds__(256) void k_sample(
    const unsigned short* __restrict__ val,   // (117360, 256) bf16
    const float* __restrict__ OFFLOG,         // (2500, 768)
    const float* __restrict__ REF,            // (6,1,2500,4,2)
    const unsigned char* __restrict__ valid,  // (6,2500)
    unsigned short* __restrict__ slots)       // (2500,256) bf16
{
  __shared__ int2  s_pack[4][NCAMS][256];
  __shared__ float s_off[512];
  __shared__ float s_ref[48];
  __shared__ int   s_valid[6];

  const int q = blockIdx.x;
  const int t = threadIdx.x;

  s_off[t]       = OFFLOG[(size_t)q * 768 + t];
  s_off[t + 256] = OFFLOG[(size_t)q * 768 + 256 + t];
  if (t < 48) s_ref[t] = REF[(size_t)(t >> 3) * (NQ * 8) + (size_t)q * 8 + (t & 7)];
  if (t < 6) s_valid[t] = valid[(size_t)t * NQ + q];

  float logit = OFFLOG[(size_t)q * 768 + 512 + t];
  float m = logit;
#pragma unroll
  for (int o = 16; o > 0; o >>= 1) m = fmaxf(m, __shfl_xor(m, o, 32));
  float e = __expf(logit - m);
  float s = e;
#pragma unroll
  for (int o = 16; o > 0; o >>= 1) s += __shfl_xor(s, o, 32);
  const float a = e / s;
  __syncthreads();

  {
    const int h1 = t >> 5, lp = t & 31, lvl = lp >> 3, p = lp & 7, z = p & 3;
    const int WW = 160 >> lvl;
    const int HH = (lvl < 3) ? (92 >> lvl) : 12;
    const int S  = (lvl == 0) ? 0 : (lvl == 1) ? 14720 : (lvl == 2) ? 18400 : 19320;
    const float Wf = (float)WW, Hf = (float)HH;
    const float ox = s_off[h1 * 64 + lp * 2];
    const float oy = s_off[h1 * 64 + lp * 2 + 1];
#pragma unroll 1
    for (int cam = 0; cam < NCAMS; ++cam) {
      if (!s_valid[cam]) continue;
      float rx = s_ref[cam * 8 + z * 2];
      float ry = s_ref[cam * 8 + z * 2 + 1];
      float x = rx * Wf + ox - 0.5f;
      float y = ry * Hf + oy - 0.5f;
      float x0f = floorf(x), y0f = floorf(y);
      float fx = x - x0f, fy = y - y0f;
      int x0 = (int)x0f, y0 = (int)y0f;
      int base = cam * LTOT + S;
#pragma unroll
      for (int dy = 0; dy < 2; ++dy) {
        int yi = y0 + dy;
        float wy = dy ? fy : 1.f - fy;
        int yc = min(max(yi, 0), HH - 1);
        bool vy = (yi >= 0) && (yi < HH);
#pragma unroll
        for (int dx = 0; dx < 2; ++dx) {
          int xi = x0 + dx;
          float wx = dx ? fx : 1.f - fx;
          int xc = min(max(xi, 0), WW - 1);
          bool vv = vy && (xi >= 0) && (xi < WW);
          float wgt = vv ? wx * wy * a : 0.f;
          int addr = (base + yc * WW + xc) * 512;
          s_pack[dy * 2 + dx][cam][t] = make_int2(addr, __float_as_int(wgt));
        }
      }
    }
  }
  __syncthreads();

  const int h = t >> 5, pp = (t >> 2) & 7, l4 = t & 3;
  const unsigned dconst = (unsigned)(h * 64 + l4 * 16);
  const char* vb = (const char*)val;
  int nvalid = s_valid[0] + s_valid[1] + s_valid[2] + s_valid[3] + s_valid[4] + s_valid[5];
  float inv = 1.f / fmaxf((float)nvalid, 1.f);

  float a0 = 0.f, a1 = 0.f, a2 = 0.f, a3 = 0.f;
  float a4 = 0.f, a5 = 0.f, a6 = 0.f, a7 = 0.f;
#pragma unroll 1
  for (int cam = 0; cam < NCAMS; ++cam) {
    if (!s_valid[cam]) continue;
#pragma unroll
    for (int it = 0; it < 4; ++it) {
      const int idx = h * 32 + it * 8 + pp;
      int2 pk0 = s_pack[0][cam][idx];
      int2 pk1 = s_pack[1][cam][idx];
      int2 pk2 = s_pack[2][cam][idx];
      int2 pk3 = s_pack[3][cam][idx];
      uint4 v0 = *(const uint4*)(vb + (size_t)((unsigned)pk0.x + dconst));
      uint4 v1 = *(const uint4*)(vb + (size_t)((unsigned)pk1.x + dconst));
      uint4 v2 = *(const uint4*)(vb + (size_t)((unsigned)pk2.x + dconst));
      uint4 v3 = *(const uint4*)(vb + (size_t)((unsigned)pk3.x + dconst));
      float w0 = __int_as_float(pk0.y), w1 = __int_as_float(pk1.y);
      float w2 = __int_as_float(pk2.y), w3 = __int_as_float(pk3.y);
      a0 += w0 * __uint_as_float(v0.x << 16);
      a1 += w0 * __uint_as_float(v0.x & 0xffff0000u);
      a2 += w0 * __uint_as_float(v0.y << 16);
      a3 += w0 * __uint_as_float(v0.y & 0xffff0000u);
      a4 += w0 * __uint_as_float(v0.z << 16);
      a5 += w0 * __uint_as_float(v0.z & 0xffff0000u);
      a6 += w0 * __uint_as_float(v0.w << 16);
      a7 += w0 * __uint_as_float(v0.w & 0xffff0000u);
      a0 += w1 * __uint_as_float(v1.x << 16);
      a1 += w1 * __uint_as_float(v1.x & 0xffff0000u);
      a2 += w1 * __uint_as_float(v1.y << 16);
      a3 += w1 * __uint_as_float(v1.y & 0xffff0000u);
      a4 += w1 * __uint_as_float(v1.z << 16);
      a5 += w1 * __uint_as_float(v1.z & 0xffff0000u);
      a6 += w1 * __uint_as_float(v1.w << 16);
      a7 += w1 * __uint_as_float(v1.w & 0xffff0000u);
      a0 += w2 * __uint_as_float(v2.x << 16);
      a1 += w2 * __uint_as_float(v2.x & 0xffff0000u);
      a2 += w2 * __uint_as_float(v2.y << 16);
      a3 += w2 * __uint_as_float(v2.y & 0xffff0000u);
      a4 += w2 * __uint_as_float(v2.z << 16);
      a5 += w2 * __uint_as_float(v2.z & 0xffff0000u);
      a6 += w2 * __uint_as_float(v2.w << 16);
      a7 += w2 * __uint_as_float(v2.w & 0xffff0000u);
      a0 += w3 * __uint_as_float(v3.x << 16);
      a1 += w3 * __uint_as_float(v3.x & 0xffff0000u);
      a2 += w3 * __uint_as_float(v3.y << 16);
      a3 += w3 * __uint_as_float(v3.y & 0xffff0000u);
      a4 += w3 * __uint_as_float(v3.z << 16);
      a5 += w3 * __uint_as_float(v3.z & 0xffff0000u);
      a6 += w3 * __uint_as_float(v3.w << 16);
      a7 += w3 * __uint_as_float(v3.w & 0xffff0000u);
    }
  }

#pragma unroll
  for (int o = 4; o <= 16; o <<= 1) {
    a0 += __shfl_xor(a0, o); a1 += __shfl_xor(a1, o);
    a2 += __shfl_xor(a2, o); a3 += __shfl_xor(a3, o);
    a4 += __shfl_xor(a4, o); a5 += __shfl_xor(a5, o);
    a6 += __shfl_xor(a6, o); a7 += __shfl_xor(a7, o);
  }
  if (pp == 0) {
    uint4 r;
    r.x = (unsigned)f2bf(a0 * inv) | ((unsigned)f2bf(a1 * inv) << 16);
    r.y = (unsigned)f2bf(a2 * inv) | ((unsigned)f2bf(a3 * inv) << 16);
    r.z = (unsigned)f2bf(a4 * inv) | ((unsigned)f2bf(a5 * inv) << 16);
    r.w = (unsigned)f2bf(a6 * inv) | ((unsigned)f2bf(a7 * inv) << 16);
    *(uint4*)&slots[(size_t)q * 256 + h * 32 + l4 * 8] = r;
  }
}

// ---------------------------------------------------------------------------
extern "C" void kernel_launch(void* const* d_in, const int* in_sizes, int n_in,
                              void* d_out, int out_size, void* d_ws, size_t ws_size,
                              hipStream_t stream) {
  const float* query     = (const float*)d_in[0];
  const float* key_feats = (const float*)d_in[1];
  const float* ref       = (const float*)d_in[2];
  const unsigned char* mask = (const unsigned char*)d_in[3];
  // d_in[4] = spatial_shapes (compile-time constants)
  const float* Wv    = (const float*)d_in[5];
  const float* bv    = (const float*)d_in[6];
  const float* Woff  = (const float*)d_in[7];
  const float* boff  = (const float*)d_in[8];
  const float* Wattn = (const float*)d_in[9];
  const float* battn = (const float*)d_in[10];
  const float* Wout  = (const float*)d_in[11];
  const float* bout  = (const float*)d_in[12];
  float* out = (float*)d_out;

  char* ws = (char*)d_ws;
  size_t off = 0;
  unsigned short* val   = (unsigned short*)(ws + off); off += (size_t)MVAL * 256 * 2;
  unsigned short* WT    = (unsigned short*)(ws + off); off += 256 * 256 * 2;
  unsigned short* WTq   = (unsigned short*)(ws + off); off += 768 * 256 * 2;
  unsigned short* WoutT = (unsigned short*)(ws + off); off += 256 * 256 * 2;
  float* OFFLOG = (float*)(ws + off); off += (size_t)NQ * 768 * 4;
  unsigned short* slots = (unsigned short*)(ws + off); off += (size_t)NQ * 256 * 2;
  unsigned char* valid  = (unsigned char*)(ws + off); off += NCAMS * NQ;

  const int MASKBLKS = (NCAMS * NQ + 255) / 256;  // 59
  hipLaunchKernelGGL(k_prep, dim3(1280 + MASKBLKS), dim3(256), 0, stream,
                     Wv, Woff, Wattn, Wout, mask, WT, WTq, WoutT, valid);
  hipLaunchKernelGGL(k_valproj, dim3((MVAL + 63) / 64), dim3(512), 0, stream,
                     key_feats, WT, bv, val);
  hipLaunchKernelGGL(k_gemm_qoff, dim3((NQ + 127) / 128, 6), dim3(256), 0, stream,
                     query, WTq, boff, battn, 512, OFFLOG, NQ, 768);
  hipLaunchKernelGGL(k_sample, dim3(NQ), dim3(256), 0, stream,
                     val, OFFLOG, ref, valid, slots);
  hipLaunchKernelGGL(k_gemm_small, dim3((NQ + 127) / 128, 2), dim3(256), 0, stream,
                     slots, WoutT, bout, bout, 1 << 30, query, out, NQ, 256, 1);
}